// Round 15
// baseline (288.882 us; speedup 1.0000x reference)
//
#include <hip/hip_runtime.h>
#include <stdint.h>

// Reformer layer: B=4 T=4096 D=512 H=8 DH=64 N_HASH=4 N_BUCKET=64 BUCKET=64 FFN=2048
// kv layout: per position row of 192 u16 = [kn 0..63 | v 64..127 | qb 128..191]
typedef unsigned short u16;
typedef __attribute__((ext_vector_type(4))) int   i32x4;
typedef __attribute__((ext_vector_type(4))) float f32x4;

__device__ __forceinline__ u16 f2bf(float x){
  unsigned int u = __float_as_uint(x);
  u += 0x7FFFu + ((u >> 16) & 1u);
  return (u16)(u >> 16);
}
__device__ __forceinline__ float bf2f(u16 h){
  return __uint_as_float(((unsigned int)h) << 16);
}
__device__ __forceinline__ unsigned int cvtpk_bf16(float lo, float hi){
  unsigned int r;
  asm("v_cvt_pk_bf16_f32 %0, %1, %2" : "=v"(r) : "v"(lo), "v"(hi));
  return r;
}
__device__ __forceinline__ f32x4 mfma16(i32x4 a, i32x4 b, f32x4 c){
  asm("v_mfma_f32_16x16x32_bf16 %0, %1, %2, %0" : "+v"(c) : "v"(a), "v"(b));
  return c;
}
__device__ __forceinline__ f32x4 acc_fence(f32x4 c){
  asm volatile("s_nop 7\ns_nop 7" : "+v"(c));
  return c;
}
__device__ __forceinline__ void gl_lds16(const void* g, void* l){
  unsigned long long ga = (unsigned long long)g;
  unsigned int la = (unsigned int)(unsigned long long)l;
  __builtin_amdgcn_global_load_lds((const __attribute__((address_space(1))) void*)ga,
                                   (__attribute__((address_space(3))) void*)la, 16, 0, 0);
}
// XCD-chunked bijective swizzle (requires n % 8 == 0)
__device__ __forceinline__ int xcd_swz(int f, int n){
  int chunk = n >> 3;
  return (f & 7) * chunk + (f >> 3);
}
// monotonic-uint transform: order-preserving for fp32 compares
__device__ __forceinline__ unsigned int f2mono(float v){
  unsigned int u = __float_as_uint(v);
  return u ^ ((unsigned int)((int)u >> 31) | 0x80000000u);
}
__device__ __forceinline__ float mono2f(unsigned int mu){
  unsigned int u = (mu & 0x80000000u) ? (mu ^ 0x80000000u) : ~mu;
  return __uint_as_float(u);
}
__device__ __forceinline__ unsigned long long shfl_xor_u64(unsigned long long x, int m){
  int lo = __shfl_xor((int)(unsigned int)(x & 0xFFFFFFFFull), m);
  int hi = __shfl_xor((int)(unsigned int)(x >> 32), m);
  return ((unsigned long long)(unsigned int)hi << 32) | (unsigned int)lo;
}

// ---------------- fused input prep: x split + all weight converts + rot ----------------
__global__ __launch_bounds__(256) void k_wprep(
    const float* __restrict__ x,
    const float* __restrict__ w_qk, const float* __restrict__ w_v,
    const float* __restrict__ w_out, const float* __restrict__ w1,
    const float* __restrict__ w2, const float* __restrict__ rot,
    u16* __restrict__ xh, u16* __restrict__ xl,
    u16* __restrict__ wqkh, u16* __restrict__ wqkl,
    u16* __restrict__ wvb, u16* __restrict__ wob,
    u16* __restrict__ w1b, u16* __restrict__ w2b,
    u16* __restrict__ rothi, u16* __restrict__ rotlo)
{
  const int bid = blockIdx.x;
  if (bid < 8192){
    int i = bid*256 + threadIdx.x;
    float4 v = ((const float4*)x)[i];
    ushort4 h, l;
    h.x=f2bf(v.x); l.x=f2bf(v.x - bf2f(h.x));
    h.y=f2bf(v.y); l.y=f2bf(v.y - bf2f(h.y));
    h.z=f2bf(v.z); l.z=f2bf(v.z - bf2f(h.z));
    h.w=f2bf(v.w); l.w=f2bf(v.w - bf2f(h.w));
    ((ushort4*)xh)[i]=h; ((ushort4*)xl)[i]=l;
    return;
  }
  if (bid >= 11008){
    int i = (bid - 11008)*256 + threadIdx.x;   // 8192 elems
    int d = i & 63, n = i >> 6;
    float v = rot[d*128 + n];
    u16 h = f2bf(v);
    rothi[i] = h; rotlo[i] = f2bf(v - bf2f(h));
    return;
  }
  const int i = (bid - 8192)*256 + threadIdx.x;
  if (i < 65536){
    float4 v = ((const float4*)w_qk)[i];
    ushort4 h, l;
    h.x=f2bf(v.x); l.x=f2bf(v.x - bf2f(h.x));
    h.y=f2bf(v.y); l.y=f2bf(v.y - bf2f(h.y));
    h.z=f2bf(v.z); l.z=f2bf(v.z - bf2f(h.z));
    h.w=f2bf(v.w); l.w=f2bf(v.w - bf2f(h.w));
    ((ushort4*)wqkh)[i]=h; ((ushort4*)wqkl)[i]=l;
    return;
  }
  const float* src; u16* dst; int j;
  if (i < 131072){ src = w_v;  dst = wvb; j = i - 65536; }
  else if (i < 196608){ src = w_out; dst = wob; j = i - 131072; }
  else if (i < 458752){ src = w1;   dst = w1b; j = i - 196608; }
  else { src = w2; dst = w2b; j = i - 458752; }
  float4 v = ((const float4*)src)[j];
  ushort4 o; o.x=f2bf(v.x); o.y=f2bf(v.y); o.z=f2bf(v.z); o.w=f2bf(v.w);
  ((ushort4*)dst)[j] = o;
}

// ---------------- 128x128 bf16 MFMA GEMM (FFN1): bias + relu, bf16 out ----------------
__global__ __launch_bounds__(256) void k_gemm(
    const u16* __restrict__ A0, const u16* __restrict__ B0,
    const float* __restrict__ bias, u16* __restrict__ Cb,
    int M, int N, int K)
{
  const int tid = threadIdx.x;
  const int l = tid & 63, w = tid >> 6;
  const int lr = l & 15, lg = l >> 4;
  int flat = blockIdx.y * gridDim.x + blockIdx.x;
  flat = xcd_swz(flat, gridDim.x * gridDim.y);
  const int m0 = (flat / gridDim.x) * 128, n0 = (flat % gridDim.x) * 128;
  const int mbase = (w >> 1) * 64, nbase = (w & 1) * 64;

  __shared__ __align__(16) u16 As[128*64];
  __shared__ __align__(16) u16 Bs[128*64];

  f32x4 zero = {0.f,0.f,0.f,0.f};
  f32x4 acc[4][4];
  #pragma unroll
  for (int i=0;i<4;i++)
    #pragma unroll
    for (int j=0;j<4;j++) acc[i][j] = zero;

  const int row_s = tid >> 3;
  const int c16   = tid & 7;

  for (int k0 = 0; k0 < K; k0 += 64){
    #pragma unroll
    for (int q=0;q<4;q++){
      int ra = q*32 + row_s;
      int cs = c16 ^ (ra & 7);
      gl_lds16(A0 + (size_t)(m0 + ra)*K + k0 + cs*8, (char*)As + q*4096 + tid*16);
      gl_lds16(B0 + (size_t)(n0 + ra)*K + k0 + cs*8, (char*)Bs + q*4096 + tid*16);
    }
    __syncthreads();
    #pragma unroll
    for (int kk=0; kk<64; kk+=32){
      i32x4 af[4], bfr[4];
      #pragma unroll
      for (int mf=0;mf<4;mf++){
        int row = mbase + mf*16 + lr;
        af[mf] = *(const i32x4*)((const char*)As + row*128 + (((kk*2) + (lg*16)) ^ ((row&7)<<4)));
      }
      #pragma unroll
      for (int nf=0;nf<4;nf++){
        int row = nbase + nf*16 + lr;
        bfr[nf] = *(const i32x4*)((const char*)Bs + row*128 + (((kk*2) + (lg*16)) ^ ((row&7)<<4)));
      }
      #pragma unroll
      for (int mf=0;mf<4;mf++)
        #pragma unroll
        for (int nf=0;nf<4;nf++)
          acc[mf][nf] = mfma16(af[mf], bfr[nf], acc[mf][nf]);
    }
    __syncthreads();
  }

  #pragma unroll
  for (int mf=0;mf<4;mf++){
    #pragma unroll
    for (int nf=0;nf<4;nf++){
      f32x4 v = acc_fence(acc[mf][nf]);
      #pragma unroll
      for (int r=0;r<4;r++){
        int m = m0 + mbase + mf*16 + lg*4 + r;
        int n = n0 + nbase + nf*16 + lr;
        float val = fmaxf(v[r] + bias[n], 0.f);
        Cb[(size_t)m*N + n] = f2bf(val);
      }
    }
  }
}

// ---------------- 64x128 bf16 MFMA GEMM (N=512 shapes) ----------------
// MODE 3: v into kv rows (+64)   MODE 4: bf16 rowmajor + bias
template<int MODE>
__global__ __launch_bounds__(256, 4) void k_gemm64(
    const u16* __restrict__ A0, const u16* __restrict__ B0,
    const float* __restrict__ bias, u16* __restrict__ Cb,
    int M, int N, int K)
{
  const int tid = threadIdx.x;
  const int l = tid & 63, w = tid >> 6;
  const int lr = l & 15, lg = l >> 4;
  int flat = xcd_swz(blockIdx.x, gridDim.x);
  const int nT = N >> 7;
  const int m0 = (flat / nT) * 64, n0 = (flat % nT) * 128;

  __shared__ __align__(16) u16 As[64*64];    // 8KB
  __shared__ __align__(16) u16 Bs[128*64];   // 16KB

  f32x4 zero = {0.f,0.f,0.f,0.f};
  f32x4 acc[4][2];
  #pragma unroll
  for (int i=0;i<4;i++)
    #pragma unroll
    for (int j=0;j<2;j++) acc[i][j] = zero;

  const int row_s = tid >> 3;   // 0..31
  const int c8    = tid & 7;

  for (int k0 = 0; k0 < K; k0 += 64){
    #pragma unroll
    for (int q=0;q<2;q++){
      int ra = q*32 + row_s;
      int cs = c8 ^ (ra & 7);
      gl_lds16(A0 + (size_t)(m0 + ra)*K + k0 + cs*8, (char*)As + q*4096 + tid*16);
    }
    #pragma unroll
    for (int q=0;q<4;q++){
      int rb = q*32 + row_s;
      int cs = c8 ^ (rb & 7);
      gl_lds16(B0 + (size_t)(n0 + rb)*K + k0 + cs*8, (char*)Bs + q*4096 + tid*16);
    }
    __syncthreads();
    #pragma unroll
    for (int kk=0; kk<64; kk+=32){
      i32x4 af[4], bfr[2];
      #pragma unroll
      for (int mf=0;mf<4;mf++){
        int row = mf*16 + lr;
        af[mf] = *(const i32x4*)((const char*)As + row*128 + (((kk*2) + (lg*16)) ^ ((row&7)<<4)));
      }
      #pragma unroll
      for (int nf=0;nf<2;nf++){
        int row = w*32 + nf*16 + lr;
        bfr[nf] = *(const i32x4*)((const char*)Bs + row*128 + (((kk*2) + (lg*16)) ^ ((row&7)<<4)));
      }
      #pragma unroll
      for (int mf=0;mf<4;mf++)
        #pragma unroll
        for (int nf=0;nf<2;nf++)
          acc[mf][nf] = mfma16(af[mf], bfr[nf], acc[mf][nf]);
    }
    __syncthreads();
  }

  #pragma unroll
  for (int mf=0;mf<4;mf++){
    #pragma unroll
    for (int nf=0;nf<2;nf++){
      f32x4 v = acc_fence(acc[mf][nf]);
      #pragma unroll
      for (int r=0;r<4;r++){
        int m = m0 + mf*16 + lg*4 + r;
        int n = n0 + w*32 + nf*16 + lr;
        float val = v[r];
        if (MODE == 4){
          val += bias[n];
          Cb[(size_t)m*N + n] = f2bf(val);
        } else {
          int b = m >> 12, t = m & 4095, h = n >> 6, d = n & 63;
          size_t pos = (((size_t)(b*8 + h)) << 12) + t;
          Cb[pos*192 + 64 + d] = f2bf(val);       // v slice of kv row
        }
      }
    }
  }
}

// ---------------- qk GEMM: 128x64 tile, 3-term split-bf16 + fused prep epilogue ----------------
__global__ __launch_bounds__(256, 3) void k_gemmqk(
    const u16* __restrict__ Ah, const u16* __restrict__ Al,
    const u16* __restrict__ Bh, const u16* __restrict__ Bl,
    u16* __restrict__ kv, u16* __restrict__ qlo)
{
  const int K = 512;
  const int tid = threadIdx.x;
  const int l = tid & 63, w = tid >> 6;
  const int lr = l & 15, lg = l >> 4;
  int flat = xcd_swz(blockIdx.x, 1024);
  const int m0 = (flat >> 3) * 128, n0 = (flat & 7) * 64;
  const int mbase = w * 32;

  __shared__ __align__(16) u16 AsH[128*64];  // 16KB
  __shared__ __align__(16) u16 AsL[128*64];  // 16KB
  __shared__ __align__(16) u16 BsH[64*64];   // 8KB
  __shared__ __align__(16) u16 BsL[64*64];   // 8KB

  f32x4 zero = {0.f,0.f,0.f,0.f};
  f32x4 acc[2][4];
  #pragma unroll
  for (int i=0;i<2;i++)
    #pragma unroll
    for (int j=0;j<4;j++) acc[i][j] = zero;

  const int row_s = tid >> 3;
  const int c16   = tid & 7;

  for (int k0 = 0; k0 < K; k0 += 64){
    #pragma unroll
    for (int q=0;q<4;q++){
      int ra = q*32 + row_s;
      int cs = c16 ^ (ra & 7);
      size_t ao = (size_t)(m0 + ra)*K + k0 + cs*8;
      gl_lds16(Ah + ao, (char*)AsH + q*4096 + tid*16);
      gl_lds16(Al + ao, (char*)AsL + q*4096 + tid*16);
    }
    #pragma unroll
    for (int q=0;q<2;q++){
      int rb = q*32 + row_s;
      int cs = c16 ^ (rb & 7);
      size_t bo2 = (size_t)(n0 + rb)*K + k0 + cs*8;
      gl_lds16(Bh + bo2, (char*)BsH + q*4096 + tid*16);
      gl_lds16(Bl + bo2, (char*)BsL + q*4096 + tid*16);
    }
    __syncthreads();
    #pragma unroll
    for (int kk=0; kk<64; kk+=32){
      i32x4 ah[2], al[2], bh2[4], bl2[4];
      #pragma unroll
      for (int mf=0;mf<2;mf++){
        int row = mbase + mf*16 + lr;
        int off = (((kk*2) + (lg*16)) ^ ((row&7)<<4));
        ah[mf] = *(const i32x4*)((const char*)AsH + row*128 + off);
        al[mf] = *(const i32x4*)((const char*)AsL + row*128 + off);
      }
      #pragma unroll
      for (int nf=0;nf<4;nf++){
        int row = nf*16 + lr;
        int off = (((kk*2) + (lg*16)) ^ ((row&7)<<4));
        bh2[nf] = *(const i32x4*)((const char*)BsH + row*128 + off);
        bl2[nf] = *(const i32x4*)((const char*)BsL + row*128 + off);
      }
      #pragma unroll
      for (int mf=0;mf<2;mf++)
        #pragma unroll
        for (int nf=0;nf<4;nf++){
          acc[mf][nf] = mfma16(ah[mf], bh2[nf], acc[mf][nf]);
          acc[mf][nf] = mfma16(al[mf], bh2[nf], acc[mf][nf]);
          acc[mf][nf] = mfma16(ah[mf], bl2[nf], acc[mf][nf]);
        }
    }
    __syncthreads();
  }

  // fused prep epilogue: each wave's 64 columns are exactly one head (n0 is 64-aligned)
  const int hh = n0 >> 6;
  #pragma unroll
  for (int mf=0;mf<2;mf++){
    f32x4 v[4];
    #pragma unroll
    for (int nf=0;nf<4;nf++) v[nf] = acc_fence(acc[mf][nf]);
    #pragma unroll
    for (int r=0;r<4;r++){
      float ss = 0.f;
      #pragma unroll
      for (int nf=0;nf<4;nf++) ss += v[nf][r]*v[nf][r];
      ss += __shfl_xor(ss, 1); ss += __shfl_xor(ss, 2);
      ss += __shfl_xor(ss, 4); ss += __shfl_xor(ss, 8);
      // fold dim_head^-0.5 AND log2(e) into kn so attn uses raw v_exp (2^x)
      float scale = 0.18033688f / fmaxf(sqrtf(ss), 1e-6f);
      int m = m0 + mbase + mf*16 + lg*4 + r;
      int b = m >> 12, t = m & 4095;
      size_t pos = (((size_t)(b*8 + hh)) << 12) + t;
      #pragma unroll
      for (int nf=0;nf<4;nf++){
        float val = v[nf][r];
        u16 hbf = f2bf(val);
        int d = nf*16 + lr;
        kv [pos*192 + d]       = f2bf(val * scale);   // kn (pre-scaled)
        kv [pos*192 + 128 + d] = hbf;                 // qb
        qlo[pos*64  + d]       = f2bf(val - bf2f(hbf));
      }
    }
  }
}

// ---------------- LSH hash: swapped-operand MFMA, lane-local argmax ----------------
__global__ __launch_bounds__(256) void k_hash2(
    const u16* __restrict__ kv, const u16* __restrict__ ql,
    const u16* __restrict__ rh, const u16* __restrict__ rl,
    int* __restrict__ bkt)
{
  const int tid = threadIdx.x;
  const int l = tid & 63, w = tid >> 6, lr = l & 15, lg = l >> 4;
  __shared__ __align__(16) u16 Rh[128*64];
  __shared__ __align__(16) u16 Rl[128*64];
  {
    const int row_s = tid >> 3, c8 = tid & 7;
    #pragma unroll
    for (int q = 0; q < 4; q++){
      int ra = q*32 + row_s;
      int cs = c8 ^ (ra & 7);
      gl_lds16(rh + ra*64 + cs*8, (char*)Rh + q*4096 + tid*16);
      gl_lds16(rl + ra*64 + cs*8, (char*)Rl + q*4096 + tid*16);
    }
  }
  const int blk = xcd_swz(blockIdx.x, gridDim.x);
  const int qrow = blk*64 + w*16 + lr;
  const size_t qoff = (size_t)qrow*192 + 128;   // qb slice of kv row
  const size_t loff = (size_t)qrow*64;
  i32x4 qhf[2], qlf[2];
  qhf[0] = *(const i32x4*)(kv + qoff + lg*8);
  qhf[1] = *(const i32x4*)(kv + qoff + 32 + lg*8);
  qlf[0] = *(const i32x4*)(ql + loff + lg*8);
  qlf[1] = *(const i32x4*)(ql + loff + 32 + lg*8);
  __syncthreads();

  f32x4 zero = {0.f,0.f,0.f,0.f};
  f32x4 acc[8];
  #pragma unroll
  for (int i=0;i<8;i++) acc[i] = zero;
  #pragma unroll
  for (int ks = 0; ks < 2; ks++){
    #pragma unroll
    for (int nf = 0; nf < 8; nf++){
      int row = nf*16 + lr;
      int off = (ks*64 + lg*16) ^ ((row & 7) << 4);
      i32x4 rhf = *(const i32x4*)((const char*)Rh + row*128 + off);
      i32x4 rlf = *(const i32x4*)((const char*)Rl + row*128 + off);
      acc[nf] = mfma16(rhf, qhf[ks], acc[nf]);
      acc[nf] = mfma16(rlf, qhf[ks], acc[nf]);
      acc[nf] = mfma16(rhf, qlf[ks], acc[nf]);
    }
  }

  const int bh = qrow >> 12, t = qrow & 4095;
  #pragma unroll
  for (int hh = 0; hh < 4; hh++){
    f32x4 v0 = acc_fence(acc[2*hh]);
    f32x4 v1 = acc_fence(acc[2*hh+1]);
    unsigned long long kmax = 0, kmin = 0;
    #pragma unroll
    for (int r = 0; r < 4; r++){
      int j0 = lg*4 + r, j1 = 16 + lg*4 + r;
      unsigned int mu0 = f2mono(v0[r]), mu1 = f2mono(v1[r]);
      unsigned long long a = ((unsigned long long)mu0 << 32) | (unsigned int)(31 - j0);
      unsigned long long b = ((unsigned long long)mu1 << 32) | (unsigned int)(31 - j1);
      if (a > kmax) kmax = a;
      if (b > kmax) kmax = b;
      unsigned long long c = ((unsigned long long)(~mu0) << 32) | (unsigned int)(31 - j0);
      unsigned long long d = ((unsigned long long)(~mu1) << 32) | (unsigned int)(31 - j1);
      if (c > kmin) kmin = c;
      if (d > kmin) kmin = d;
    }
    #pragma unroll
    for (int msk = 16; msk < 64; msk <<= 1){
      unsigned long long o1 = shfl_xor_u64(kmax, msk); if (o1 > kmax) kmax = o1;
      unsigned long long o2 = shfl_xor_u64(kmin, msk); if (o2 > kmin) kmin = o2;
    }
    if (lg == 0){
      float vmax = mono2f((unsigned int)(kmax >> 32));
      int jmax = 31 - (int)(kmax & 0xFFFFFFFFull);
      float vmin = mono2f(~(unsigned int)(kmin >> 32));
      int jmin = 31 - (int)(kmin & 0xFFFFFFFFull);
      int bucket = (vmax >= -vmin) ? jmax : 32 + jmin;
      bkt[((size_t)(bh*4 + hh) << 12) + t] = bucket;
    }
  }
}

// ---------------- stable counting sort per (bh, round) ----------------
__global__ __launch_bounds__(64) void k_sort(const int* __restrict__ buckets, int* __restrict__ st){
  const int grp = blockIdx.x;
  const int t = threadIdx.x;
  __shared__ int bkL[4096];
  __shared__ int hist[64][65];
  __shared__ int tot[64];
  const size_t gbase = ((size_t)grp) << 12;
  for (int i=0;i<64;i++)
    bkL[i*64 + t] = buckets[gbase + i*64 + t];   // coalesced
  #pragma unroll
  for (int b=0;b<64;b++) hist[t][b] = 0;
  __syncthreads();
  for (int i=0;i<64;i++){
    int b = bkL[t*64 + i];
    hist[t][b]++;
  }
  __syncthreads();
  { int run = 0;
    for (int tt=0; tt<64; tt++){ int v = hist[tt][t]; hist[tt][t] = run; run += v; }
    tot[t] = run; }
  __syncthreads();
  { int v = tot[t]; int incl = v;
    #pragma unroll
    for (int d=1; d<64; d<<=1){ int n = __shfl_up(incl, d, 64); if (t >= d) incl += n; }
    tot[t] = incl - v; }
  __syncthreads();
  const size_t obase = (((size_t)(grp>>2)) << 14) + ((size_t)(grp&3) << 12);
  for (int i=0;i<64;i++){
    int e = t*64 + i;
    int b = bkL[e];
    int dest = tot[b] + hist[t][b];
    hist[t][b]++;
    st[obase + dest] = e;
  }
}

// ---------------- chunked LSH attention: 2 chunks/block, pipelined with K-reuse ----------------
__global__ __launch_bounds__(256, 4) void k_attn(
    const u16* __restrict__ kv,
    const int* __restrict__ st, float* __restrict__ lgt_out, u16* __restrict__ bo)
{
  int flat = xcd_swz(blockIdx.x, 4096);
  const int cpair = flat & 127, bh = flat >> 7;
  const int tid = threadIdx.x;
  const int l = tid & 63, w = tid >> 6, lr = l & 15, lg = l >> 4;

  __shared__ __align__(16) u16 Ks[128*64];   // 16KB
  __shared__ __align__(16) u16 Vt[64*128];   // 16KB, XOR-swizzled rows of 256B

  const size_t stbase = ((size_t)bh) << 14;
  const size_t kvbase = (((size_t)bh) << 12) * 192;

  const int rsub = l >> 3, c8 = l & 7;
  const int pp = tid & 63, db = tid >> 6;
  const int q5 = pp & 15;
  const int K0 = (pp >> 4)*32 + 16*((q5 >> 1) & 1) + 4*(q5 >> 2) + 2*(q5 & 1);

  int c = cpair*2;

  // ---- prologue: stage chunk c (full window) ----
  {
    const int cprev = (c + 255) & 255;
    #pragma unroll
    for (int q2 = 0; q2 < 4; q2++){
      int row = w*32 + q2*8 + rsub;
      int cc = (row < 64) ? c : cprev;
      int pos = st[stbase + (cc << 6) + (row & 63)];
      int cs = c8 ^ (row & 7);
      gl_lds16(kv + kvbase + (size_t)pos*192 + cs*8,
               (char*)Ks + (w*4 + q2)*1024 + l*16);
    }
    int cc0 = (K0 < 64) ? c : cprev;
    int p0 = st[stbase + (cc0 << 6) + (K0 & 63)];
    int p1 = st[stbase + (cc0 << 6) + ((K0 + 1) & 63)];
    const u16* r0 = kv + kvbase + (size_t)p0*192 + 64 + db*16;
    const u16* r1 = kv + kvbase + (size_t)p1*192 + 64 + db*16;
    uint4 a0 = *(const uint4*)r0, a1 = *(const uint4*)(r0 + 8);
    uint4 b0 = *(const uint4*)r1, b1 = *(const uint4*)(r1 + 8);
    uint av[8] = {a0.x,a0.y,a0.z,a0.w,a1.x,a1.y,a1.z,a1.w};
    uint bv[8] = {b0.x,b0.y,b0.z,b0.w,b1.x,b1.y,b1.z,b1.w};
    #pragma unroll
    for (int dd = 0; dd < 16; dd++){
      uint lo = (av[dd>>1] >> ((dd&1)*16)) & 0xFFFFu;
      uint hi = (bv[dd>>1] >> ((dd&1)*16)) & 0xFFFFu;
      int row = db*16 + dd;
      *(uint*)((char*)Vt + row*256 + ((pp*4) ^ ((row & 7) << 5))) = lo | (hi << 16);
    }
  }
  int pos_q = st[stbase + (c << 6) + (w*16 + lr)];
  i32x4 qf[2];
  qf[0] = *(const i32x4*)(kv + kvbase + (size_t)pos_q*192 + 128 + lg*8);
  qf[1] = *(const i32x4*)(kv + kvbase + (size_t)pos_q*192 + 128 + 32 + lg*8);
  bool bdry = (c & 63) == 0;
  int pkprev[4][4];
  if (bdry){
    const int cprev = (c + 255) & 255;
    #pragma unroll
    for (int nf2=0; nf2<4; nf2++)
      #pragma unroll
      for (int r=0;r<4;r++)
        pkprev[nf2][r] = st[stbase + (cprev << 6) + nf2*16 + lg*4 + r];
  }
  __syncthreads();                                   // B0: Ks/Vt(c) ready

  int pos_q_n = 0;
  i32x4 qfn[2];
  uint avn[8], bvn[8];

  #pragma unroll
  for (int it = 0; it < 2; ++it){
    const int rnd = c >> 6;
    f32x4 zero = {0.f,0.f,0.f,0.f};
    f32x4 s[8];
    #pragma unroll
    for (int i=0;i<8;i++) s[i] = zero;
    __builtin_amdgcn_s_setprio(1);
    #pragma unroll
    for (int ks = 0; ks < 2; ks++){
      #pragma unroll
      for (int nf = 0; nf < 8; nf++){
        int row = nf*16 + lr;
        i32x4 kf = *(const i32x4*)((const char*)Ks + row*128 + ((ks*64 + lg*16) ^ ((row&7)<<4)));
        s[nf] = mfma16(kf, qf[ks], s[nf]);
      }
    }
    __builtin_amdgcn_s_setprio(0);

    if (it == 0){
      // Ks reuse: chunk c+1's rows 64..127 are chunk c's rows 0..63 (same positions,
      // same (row&7) XOR swizzle) => plain byte copy [0,8K) -> [8K,16K)
      i32x4 kmv0 = *(const i32x4*)((const char*)Ks + tid*32);
      i32x4 kmv1 = *(const i32x4*)((const char*)Ks + tid*32 + 16);
      __syncthreads();                               // B1: all QK reads + copy-reads done
      *(i32x4*)((char*)Ks + 8192 + tid*32)      = kmv0;
      *(i32x4*)((char*)Ks + 8192 + tid*32 + 16) = kmv1;
      const int c1 = c + 1;                          // c1's window = {c, c1}; prev = c
      // new K rows 0..63 (chunk c1) via DMA — only waves 0,1 own these rows
      #pragma unroll
      for (int q2 = 0; q2 < 4; q2++){
        int row = w*32 + q2*8 + rsub;
        if (row < 64){
          int pos = st[stbase + (c1 << 6) + row];
          int cs = c8 ^ (row & 7);
          gl_lds16(kv + kvbase + (size_t)pos*192 + cs*8,
                   (char*)Ks + (w*4 + q2)*1024 + l*16);
        }
      }
      // prefetch c1 V + Q to registers (latency hidden under softmax+PV below)
      {
        int cc0 = (K0 < 64) ? c1 : c;
        int p0 = st[stbase + (cc0 << 6) + (K0 & 63)];
        int p1 = st[stbase + (cc0 << 6) + ((K0 + 1) & 63)];
        const u16* r0 = kv + kvbase + (size_t)p0*192 + 64 + db*16;
        const u16* r1 = kv + kvbase + (size_t)p1*192 + 64 + db*16;
        uint4 a0 = *(const uint4*)r0, a1 = *(const uint4*)(r0 + 8);
        uint4 b0 = *(const uint4*)r1, b1 = *(const uint4*)(r1 + 8);
        avn[0]=a0.x; avn[1]=a0.y; avn[2]=a0.z; avn[3]=a0.w;
        avn[4]=a1.x; avn[5]=a1.y; avn[6]=a1.z; avn[7]=a1.w;
        bvn[0]=b0.x; bvn[1]=b0.y; bvn[2]=b0.z; bvn[3]=b0.w;
        bvn[4]=b1.x; bvn[5]=b1.y; bvn[6]=b1.z; bvn[7]=b1.w;
      }
      pos_q_n = st[stbase + (c1 << 6) + (w*16 + lr)];
      qfn[0] = *(const i32x4*)(kv + kvbase + (size_t)pos_q_n*192 + 128 + lg*8);
      qfn[1] = *(const i32x4*)(kv + kvbase + (size_t)pos_q_n*192 + 128 + 32 + lg*8);
    }

    // max-free softmax: S pre-scaled by 0.125*log2e -> p = 2^S, cannot overflow
    float p[8][4];
    float sum = 0.f;
    #pragma unroll
    for (int nf=0;nf<8;nf++){
      f32x4 t = acc_fence(s[nf]);
      #pragma unroll
      for (int r=0;r<4;r++){
        float e = __builtin_amdgcn_exp2f(t[r]);
        if (nf == w && (lg*4 + r) == lr) e = 0.f;                        // self (same slot)
        if (nf >= 4 && bdry && pkprev[nf-4][r] == pos_q) e = 0.f;        // cross-round same token
        p[nf][r] = e;
        sum += e;
      }
    }
    sum += __shfl_xor(sum, 16);
    sum += __shfl_xor(sum, 32);
    float lv = logf(sum);
    float inv = 1.f / sum;
    if (l < 16)
      lgt_out[((((size_t)bh) << 12) + pos_q)*4 + rnd] = lv;

    i32x4 pa[4];
    #pragma unroll
    for (int ks=0;ks<4;ks++){
      uint w0 = cvtpk_bf16(p[2*ks][0],   p[2*ks][1]);
      uint w1 = cvtpk_bf16(p[2*ks][2],   p[2*ks][3]);
      uint w2 = cvtpk_bf16(p[2*ks+1][0], p[2*ks+1][1]);
      uint w3 = cvtpk_bf16(p[2*ks+1][2], p[2*ks+1][3]);
      i32x4 t = {(int)w0,(int)w1,(int)w2,(int)w3};
      pa[ks] = t;
    }

    f32x4 o[4];
    #pragma unroll
    for (int i=0;i<4;i++) o[i] = zero;
    __builtin_amdgcn_s_setprio(1);
    #pragma unroll
    for (int ks=0;ks<4;ks++){
      #pragma unroll
      for (int nf=0;nf<4;nf++){
        int row = nf*16 + lr;
        i32x4 vf = *(const i32x4*)((const char*)Vt + row*256 + ((ks*64 + lg*16) ^ ((row & 7) << 5)));
        o[nf] = mfma16(pa[ks], vf, o[nf]);
      }
    }
    __builtin_amdgcn_s_setprio(0);
    float invq[4]; int posq[4];
    #pragma unroll
    for (int r=0;r<4;r++){
      invq[r] = __shfl(inv, lg*4 + r, 64);
      posq[r] = __shfl(pos_q, lg*4 + r, 64);
    }
    #pragma unroll
    for (int nf=0;nf<4;nf++){
      f32x4 ov = acc_fence(o[nf]);
      #pragma unroll
      for (int r=0;r<4;r++){
        bo[((((size_t)bh << 12) + posq[r]))*256 + rnd*64 + nf*16 + lr] = f2bf(ov[r] * invq[r]);
      }
    }

    if (it == 0){
      __syncthreads();                               // B2: Vt reads done; drains c1 K DMA + V/Q loads
      #pragma unroll
      for (int dd = 0; dd < 16; dd++){
        uint lo = (avn[dd>>1] >> ((dd&1)*16)) & 0xFFFFu;
        uint hi = (bvn[dd>>1] >> ((dd&1)*16)) & 0xFFFFu;
        int row = db*16 + dd;
        *(uint*)((char*)Vt + row*256 + ((pp*4) ^ ((row & 7) << 5))) = lo | (hi << 16);
      }
      c = c + 1;
      pos_q = pos_q_n;
      qf[0] = qfn[0]; qf[1] = qfn[1];
      bdry = false;                                  // odd chunk is never a round boundary
      __syncthreads();                               // B3: Ks/Vt(c+1) ready
    }
  }
}

// ---------------- combine hash rounds (token-major bo/lgt) ----------------
__global__ __launch_bounds__(256) void k_combine(const u16* __restrict__ bo, const float* __restrict__ lgt,
                                                 u16* __restrict__ attn){
  const int wid = blockIdx.x * 4 + (threadIdx.x >> 6);
  const int l = threadIdx.x & 63;
  const int bh = wid >> 12, t = wid & 4095;
  const size_t tb = (((size_t)bh) << 12) + t;
  float4 lg4 = *(const float4*)(lgt + tb*4);
  float m = fmaxf(fmaxf(lg4.x,lg4.y), fmaxf(lg4.z,lg4.w));
  float w0 = __expf(lg4.x-m), w1 = __expf(lg4.y-m), w2 = __expf(lg4.z-m), w3 = __expf(lg4.w-m);
  float inv = 1.f / (w0+w1+w2+w3);
  const u16* bp = bo + tb*256;
  float o = w0 * bf2f(bp[l]) + w1 * bf2f(bp[64+l]) + w2 * bf2f(bp[128+l]) + w3 * bf2f(bp[192+l]);
  o *= inv;
  int b = bh >> 3, h = bh & 7;
  attn[((((size_t)b) << 12) + t) * 512 + h*64 + l] = f2bf(o);
}

// ---------------- residual + LayerNorm: a always bf16 ----------------
// RESF=1: res fp32 (x), write bf16 ob. RESF=0: res bf16 (hb), write fp32 of.
template<int RESF>
__global__ __launch_bounds__(256) void k_ln(const u16* __restrict__ a,
                                            const float* __restrict__ resf, const u16* __restrict__ resb,
                                            const float* __restrict__ g, const float* __restrict__ bb,
                                            float* __restrict__ of, u16* __restrict__ ob){
  const int row = blockIdx.x*4 + (threadIdx.x >> 6);
  const int l = threadIdx.x & 63;
  const size_t base = (size_t)row*512 + l*8;
  uint4 aa = *(const uint4*)(a + base);
  uint aw[4] = {aa.x, aa.y, aa.z, aa.w};
  float av[8];
  #pragma unroll
  for (int j=0;j<4;j++){
    av[2*j]   = bf2f((u16)(aw[j] & 0xFFFF));
    av[2*j+1] = bf2f((u16)(aw[j] >> 16));
  }
  float rv[8];
  if (RESF){
    float4 r0 = *(const float4*)(resf + base);
    float4 r1 = *(const float4*)(resf + base + 4);
    rv[0]=r0.x; rv[1]=r0.y; rv[2]=r0.z; rv[3]=r0.w;
    rv[4]=r1.x; rv[5]=r1.y; rv[6]=r1.z; rv[7]=r1.w;
  } else {
    uint4 rr = *(const uint4*)(resb + base);
    uint rw[4] = {rr.x, rr.y, rr.z, rr.w};
    #pragma unroll
    for (int j=0;j<4;j++){
      rv[2*j]   = bf2f((u16)(rw[j] & 0xFFFF));
      rv[2*j+1] = bf2f((u16)(rw[j] >> 16));
    }
  }
  float v[8];
  #pragma unroll
  for (int j=0;j<8;j++) v[j] = av[j] + rv[j];
  float sum = 0.f;
  #pragma unroll
  for (int j=0;j<8;j++) sum += v[j];
  #pragma unroll
  for (int msk=1; msk<64; msk<<=1) sum += __shfl_xor(sum, msk);
  float mean = sum * (1.f/512.f);
  float ss = 0.f;
  #pragma unroll
  for (int j=0;j<8;j++){ float d = v[j]-mean; ss += d*d; }
  #pragma unroll
  for (int msk=1; msk<64; msk<<=1) ss += __shfl_xor(ss, msk);
  float rstd = rsqrtf(ss * (1.f/512.f) + 1e-6f);
  float4 g0 = *(const float4*)(g + l*8),  g1 = *(const float4*)(g + l*8 + 4);
  float4 b0 = *(const float4*)(bb + l*8), b1 = *(const float4*)(bb + l*8 + 4);
  float gv[8] = {g0.x,g0.y,g0.z,g0.w,g1.x,g1.y,g1.z,g1.w};
  float bv[8] = {b0.x,b0.y,b0.z,b0.w,b1.x,b1.y,b1.z,b1.w};
  float y[8];
  #pragma unroll
  for (int j=0;j<8;j++) y[j] = (v[j]-mean)*rstd*gv[j] + bv[j];
  if (RESF){
    #pragma unroll
    for (int j=0;j<8;j++) ob[base+j] = f2bf(y[j]);
  } else {
    #pragma unroll
    for (int j=0;j<8;j++) of[base+j] = y[j];
  }
}

extern "C" void kernel_launch(void* const* d_in, const int* in_sizes, int n_in,
                              void* d_out, int out_size, void* d_ws, size_t ws_size,
                              hipStream_t stream) {
  const float* x     = (const float*)d_in[0];
  const float* rot   = (const float*)d_in[1];
  const float* w_qk  = (const float*)d_in[2];
  const float* w_v   = (const float*)d_in[3];
  const float* w_out = (const float*)d_in[4];
  const float* b_out = (const float*)d_in[5];
  const float* ln1_g = (const float*)d_in[6];
  const float* ln1_b = (const float*)d_in[7];
  const float* w1    = (const float*)d_in[8];
  const float* b1    = (const float*)d_in[9];
  const float* w2    = (const float*)d_in[10];
  const float* b2    = (const float*)d_in[11];
  const float* ln2_g = (const float*)d_in[12];
  const float* ln2_b = (const float*)d_in[13];
  float* out = (float*)d_out;

  char* p = (char*)d_ws;
  u16*   xh   = (u16*)(p);                    // x-hi   | later: hb (bf16 h)
  u16*   xl   = (u16*)(p + 16777216);         // x-lo   | later: attnc, then f bf16
  u16*   wqkh = (u16*)(p + 33554432);
  u16*   wqkl = (u16*)(p + 34078720);
  u16*   wvb  = (u16*)(p + 34603008);
  u16*   wob  = (u16*)(p + 35127296);
  u16*   w1b  = (u16*)(p + 35651584);
  u16*   w2b  = (u16*)(p + 37748736);
  u16*   kvb  = (u16*)(p + 39845888);         // 131072 x 192 u16 = 50.3MB  | later: projb
  int*   bkt  = (int*)(p + 90177536);
  int*   stb  = (int*)(p + 92274688);
  float* lgt  = (float*)(p + 94371840);
  u16*   bo   = (u16*)(p + 96468992);         // 64MB | early: qlo + rot, later: ffn hidden
  // aliases (non-overlapping lifetimes)
  u16*   qlo   = bo;                          // bo[0..16MB): dead before k_attn writes bo
  u16*   rothi = (u16*)(p + 96468992 + 16777216);          // bo+16MB, 16KB
  u16*   rotlo = (u16*)(p + 96468992 + 16777216 + 16384);  // consumed by hash before attn
  u16*   attnc = xl;
  u16*   projb = kvb;                         // out-proj bf16 (kv dead after attn)
  u16*   fb    = xl;                          // FFN2 bf16 (xl dead after out-proj)
  u16*   hb    = xh;
  u16*   hid   = bo;

  // 1) x split + all weight converts + rot transpose/split in one dispatch
  k_wprep<<<11040, 256, 0, stream>>>(x, w_qk, w_v, w_out, w1, w2, rot,
                                     xh, xl, wqkh, wqkl, wvb, wob, w1b, w2b, rothi, rotlo);
  // 2) qk GEMM (128x64 tile, 3-term split) + fused prep -> kv(kn,qb) + qlo
  k_gemmqk<<<1024, 256, 0, stream>>>(xh, xl, wqkh, wqkl, kvb, qlo);
  // 3) v = x @ w_v^T -> kv(+64 slice)
  k_gemm64<3><<<1024, 256, 0, stream>>>(xh, wvb, nullptr, kvb, 16384, 512, 512);
  // 4) LSH hash: S^T = rot x qk (3-term split), lane-local argmax -> buckets
  k_hash2<<<2048, 256, 0, stream>>>(kvb, qlo, rothi, rotlo, bkt);
  // 5) stable counting sort per (bh, round)
  k_sort<<<128, 64, 0, stream>>>(bkt, stb);
  // 6) chunked attention: 2 chunks/block, pipelined + K-reuse
  k_attn<<<4096, 256, 0, stream>>>(kvb, stb, lgt, bo);
  // 7) combine rounds -> (b,t,512) bf16
  k_combine<<<32768, 256, 0, stream>>>(bo, lgt, attnc);
  // 8) out projection (+bias) -> bf16 projb — 64x128 tiles
  k_gemm64<4><<<1024, 256, 0, stream>>>(attnc, wob, b_out, projb, 16384, 512, 512);
  // 9) h = LN(proj + x) -> bf16 hb
  k_ln<1><<<4096, 256, 0, stream>>>(projb, x, nullptr, ln1_g, ln1_b, nullptr, hb);
  // 10) hidden = relu(h @ w1^T + b1) bf16 — 128x128, 2048 blocks
  k_gemm<<<dim3(16,128), 256, 0, stream>>>(hb, w1b, b1, hid, 16384, 2048, 512);
  // 11) f = hidden @ w2^T + b2 -> bf16 fb — 64x128 tiles
  k_gemm64<4><<<1024, 256, 0, stream>>>(hid, w2b, b2, fb, 16384, 512, 2048);
  // 12) out = LN(f + h) -> fp32 d_out
  k_ln<0><<<4096, 256, 0, stream>>>(fb, nullptr, hb, ln2_g, ln2_b, out, nullptr);
}

// Round 16
// 282.973 us; speedup vs baseline: 1.0209x; 1.0209x over previous
//
#include <hip/hip_runtime.h>
#include <stdint.h>

// Reformer layer: B=4 T=4096 D=512 H=8 DH=64 N_HASH=4 N_BUCKET=64 BUCKET=64 FFN=2048
typedef unsigned short u16;
typedef __attribute__((ext_vector_type(4))) int   i32x4;
typedef __attribute__((ext_vector_type(4))) float f32x4;

__device__ __forceinline__ u16 f2bf(float x){
  unsigned int u = __float_as_uint(x);
  u += 0x7FFFu + ((u >> 16) & 1u);
  return (u16)(u >> 16);
}
__device__ __forceinline__ float bf2f(u16 h){
  return __uint_as_float(((unsigned int)h) << 16);
}
__device__ __forceinline__ unsigned int cvtpk_bf16(float lo, float hi){
  unsigned int r;
  asm("v_cvt_pk_bf16_f32 %0, %1, %2" : "=v"(r) : "v"(lo), "v"(hi));
  return r;
}
__device__ __forceinline__ f32x4 mfma16(i32x4 a, i32x4 b, f32x4 c){
  asm("v_mfma_f32_16x16x32_bf16 %0, %1, %2, %0" : "+v"(c) : "v"(a), "v"(b));
  return c;
}
__device__ __forceinline__ f32x4 acc_fence(f32x4 c){
  asm volatile("s_nop 7\ns_nop 7" : "+v"(c));
  return c;
}
__device__ __forceinline__ void gl_lds16(const void* g, void* l){
  unsigned long long ga = (unsigned long long)g;
  unsigned int la = (unsigned int)(unsigned long long)l;
  __builtin_amdgcn_global_load_lds((const __attribute__((address_space(1))) void*)ga,
                                   (__attribute__((address_space(3))) void*)la, 16, 0, 0);
}
// XCD-chunked bijective swizzle (requires n % 8 == 0)
__device__ __forceinline__ int xcd_swz(int f, int n){
  int chunk = n >> 3;
  return (f & 7) * chunk + (f >> 3);
}
// monotonic-uint transform: order-preserving for fp32 compares
__device__ __forceinline__ unsigned int f2mono(float v){
  unsigned int u = __float_as_uint(v);
  return u ^ ((unsigned int)((int)u >> 31) | 0x80000000u);
}
__device__ __forceinline__ float mono2f(unsigned int mu){
  unsigned int u = (mu & 0x80000000u) ? (mu ^ 0x80000000u) : ~mu;
  return __uint_as_float(u);
}
__device__ __forceinline__ unsigned long long shfl_xor_u64(unsigned long long x, int m){
  int lo = __shfl_xor((int)(unsigned int)(x & 0xFFFFFFFFull), m);
  int hi = __shfl_xor((int)(unsigned int)(x >> 32), m);
  return ((unsigned long long)(unsigned int)hi << 32) | (unsigned int)lo;
}

// ---------------- x split (big) ----------------
__global__ __launch_bounds__(256) void k_split(const float* __restrict__ in, u16* __restrict__ hi, u16* __restrict__ lo, int n4){
  int i = blockIdx.x*256 + threadIdx.x;
  if (i >= n4) return;
  float4 v = ((const float4*)in)[i];
  ushort4 h, l;
  h.x=f2bf(v.x); l.x=f2bf(v.x - bf2f(h.x));
  h.y=f2bf(v.y); l.y=f2bf(v.y - bf2f(h.y));
  h.z=f2bf(v.z); l.z=f2bf(v.z - bf2f(h.z));
  h.w=f2bf(v.w); l.w=f2bf(v.w - bf2f(h.w));
  ((ushort4*)hi)[i]=h; ((ushort4*)lo)[i]=l;
}

// ---------------- fused weight prep ----------------
__global__ __launch_bounds__(256) void k_wprep(
    const float* __restrict__ w_qk, const float* __restrict__ w_v,
    const float* __restrict__ w_out, const float* __restrict__ w1,
    const float* __restrict__ w2, const float* __restrict__ rot,
    u16* __restrict__ wqkh, u16* __restrict__ wqkl,
    u16* __restrict__ wvb, u16* __restrict__ wob,
    u16* __restrict__ w1b, u16* __restrict__ w2b,
    u16* __restrict__ rothi, u16* __restrict__ rotlo)
{
  const int bid = blockIdx.x;
  if (bid >= 2816){
    int i = (bid - 2816)*256 + threadIdx.x;   // 8192 elems
    int d = i & 63, n = i >> 6;
    float v = rot[d*128 + n];
    u16 h = f2bf(v);
    rothi[i] = h; rotlo[i] = f2bf(v - bf2f(h));
    return;
  }
  const int i = bid*256 + threadIdx.x;
  if (i < 65536){
    float4 v = ((const float4*)w_qk)[i];
    ushort4 h, l;
    h.x=f2bf(v.x); l.x=f2bf(v.x - bf2f(h.x));
    h.y=f2bf(v.y); l.y=f2bf(v.y - bf2f(h.y));
    h.z=f2bf(v.z); l.z=f2bf(v.z - bf2f(h.z));
    h.w=f2bf(v.w); l.w=f2bf(v.w - bf2f(h.w));
    ((ushort4*)wqkh)[i]=h; ((ushort4*)wqkl)[i]=l;
    return;
  }
  const float* src; u16* dst; int j;
  if (i < 131072){ src = w_v;  dst = wvb; j = i - 65536; }
  else if (i < 196608){ src = w_out; dst = wob; j = i - 131072; }
  else if (i < 458752){ src = w1;   dst = w1b; j = i - 196608; }
  else { src = w2; dst = w2b; j = i - 458752; }
  float4 v = ((const float4*)src)[j];
  ushort4 o; o.x=f2bf(v.x); o.y=f2bf(v.y); o.z=f2bf(v.z); o.w=f2bf(v.w);
  ((ushort4*)dst)[j] = o;
}

// ---------------- generic bf16 MFMA GEMM: C = A * B^T ----------------
// MODE 1: bf16 rowmajor, bias+relu   MODE 3: bf16 head-layout (v)   MODE 4: bf16 rowmajor + bias
template<int MODE>
__global__ __launch_bounds__(256) void k_gemm(
    const u16* __restrict__ A0, const u16* __restrict__ B0,
    const float* __restrict__ bias,
    float* __restrict__ Cf, u16* __restrict__ Cb,
    int M, int N, int K)
{
  const int tid = threadIdx.x;
  const int l = tid & 63, w = tid >> 6;
  const int lr = l & 15, lg = l >> 4;
  int flat = blockIdx.y * gridDim.x + blockIdx.x;
  flat = xcd_swz(flat, gridDim.x * gridDim.y);
  const int m0 = (flat / gridDim.x) * 128, n0 = (flat % gridDim.x) * 128;
  const int mbase = (w >> 1) * 64, nbase = (w & 1) * 64;

  __shared__ __align__(16) u16 As[128*64];
  __shared__ __align__(16) u16 Bs[128*64];

  f32x4 zero = {0.f,0.f,0.f,0.f};
  f32x4 acc[4][4];
  #pragma unroll
  for (int i=0;i<4;i++)
    #pragma unroll
    for (int j=0;j<4;j++) acc[i][j] = zero;

  const int row_s = tid >> 3;
  const int c16   = tid & 7;

  for (int k0 = 0; k0 < K; k0 += 64){
    #pragma unroll
    for (int q=0;q<4;q++){
      int ra = q*32 + row_s;
      int cs = c16 ^ (ra & 7);
      gl_lds16(A0 + (size_t)(m0 + ra)*K + k0 + cs*8, (char*)As + q*4096 + tid*16);
      gl_lds16(B0 + (size_t)(n0 + ra)*K + k0 + cs*8, (char*)Bs + q*4096 + tid*16);
    }
    __syncthreads();
    #pragma unroll
    for (int kk=0; kk<64; kk+=32){
      i32x4 af[4], bfr[4];
      #pragma unroll
      for (int mf=0;mf<4;mf++){
        int row = mbase + mf*16 + lr;
        af[mf] = *(const i32x4*)((const char*)As + row*128 + (((kk*2) + (lg*16)) ^ ((row&7)<<4)));
      }
      #pragma unroll
      for (int nf=0;nf<4;nf++){
        int row = nbase + nf*16 + lr;
        bfr[nf] = *(const i32x4*)((const char*)Bs + row*128 + (((kk*2) + (lg*16)) ^ ((row&7)<<4)));
      }
      #pragma unroll
      for (int mf=0;mf<4;mf++)
        #pragma unroll
        for (int nf=0;nf<4;nf++)
          acc[mf][nf] = mfma16(af[mf], bfr[nf], acc[mf][nf]);
    }
    __syncthreads();
  }

  #pragma unroll
  for (int mf=0;mf<4;mf++){
    #pragma unroll
    for (int nf=0;nf<4;nf++){
      f32x4 v = acc_fence(acc[mf][nf]);
      #pragma unroll
      for (int r=0;r<4;r++){
        int m = m0 + mbase + mf*16 + lg*4 + r;
        int n = n0 + nbase + nf*16 + lr;
        float val = v[r];
        if (MODE == 1){
          val += bias[n];
          val = fmaxf(val, 0.f);
          Cb[(size_t)m*N + n] = f2bf(val);
        } else if (MODE == 4){
          val += bias[n];
          Cb[(size_t)m*N + n] = f2bf(val);
        } else {
          int b = m >> 12, t = m & 4095, h = n >> 6, d = n & 63;
          size_t idx = ((((size_t)(b*8 + h)) << 12) + t)*64 + d;
          Cb[idx] = f2bf(val);
        }
      }
    }
  }
}

// ---------------- qk GEMM: single-pass 3-term split-bf16 + fused prep epilogue ----------------
// out: qb (bf16 hi), qlo (bf16 lo), kn (normalized * 0.125*log2e, bf16), all head-layout
__global__ __launch_bounds__(256) void k_gemmqk(
    const u16* __restrict__ Ah, const u16* __restrict__ Al,
    const u16* __restrict__ Bh, const u16* __restrict__ Bl,
    u16* __restrict__ qb, u16* __restrict__ qlo, u16* __restrict__ kn)
{
  const int K = 512;
  const int tid = threadIdx.x;
  const int l = tid & 63, w = tid >> 6;
  const int lr = l & 15, lg = l >> 4;
  int flat = blockIdx.y * gridDim.x + blockIdx.x;
  flat = xcd_swz(flat, gridDim.x * gridDim.y);
  const int m0 = (flat >> 2) * 128, n0 = (flat & 3) * 128;
  const int mbase = (w >> 1) * 64, nbase = (w & 1) * 64;

  __shared__ __align__(16) u16 AsH[128*64];
  __shared__ __align__(16) u16 AsL[128*64];
  __shared__ __align__(16) u16 BsH[128*64];
  __shared__ __align__(16) u16 BsL[128*64];

  f32x4 zero = {0.f,0.f,0.f,0.f};
  f32x4 acc[4][4];
  #pragma unroll
  for (int i=0;i<4;i++)
    #pragma unroll
    for (int j=0;j<4;j++) acc[i][j] = zero;

  const int row_s = tid >> 3;
  const int c16   = tid & 7;

  for (int k0 = 0; k0 < K; k0 += 64){
    #pragma unroll
    for (int q=0;q<4;q++){
      int ra = q*32 + row_s;
      int cs = c16 ^ (ra & 7);
      size_t ao = (size_t)(m0 + ra)*K + k0 + cs*8;
      size_t bo2 = (size_t)(n0 + ra)*K + k0 + cs*8;
      gl_lds16(Ah + ao, (char*)AsH + q*4096 + tid*16);
      gl_lds16(Al + ao, (char*)AsL + q*4096 + tid*16);
      gl_lds16(Bh + bo2, (char*)BsH + q*4096 + tid*16);
      gl_lds16(Bl + bo2, (char*)BsL + q*4096 + tid*16);
    }
    __syncthreads();
    #pragma unroll
    for (int kk=0; kk<64; kk+=32){
      i32x4 ah[4], al[4], bh2[4], bl2[4];
      #pragma unroll
      for (int mf=0;mf<4;mf++){
        int row = mbase + mf*16 + lr;
        int off = (((kk*2) + (lg*16)) ^ ((row&7)<<4));
        ah[mf] = *(const i32x4*)((const char*)AsH + row*128 + off);
        al[mf] = *(const i32x4*)((const char*)AsL + row*128 + off);
      }
      #pragma unroll
      for (int nf=0;nf<4;nf++){
        int row = nbase + nf*16 + lr;
        int off = (((kk*2) + (lg*16)) ^ ((row&7)<<4));
        bh2[nf] = *(const i32x4*)((const char*)BsH + row*128 + off);
        bl2[nf] = *(const i32x4*)((const char*)BsL + row*128 + off);
      }
      #pragma unroll
      for (int mf=0;mf<4;mf++)
        #pragma unroll
        for (int nf=0;nf<4;nf++){
          acc[mf][nf] = mfma16(ah[mf], bh2[nf], acc[mf][nf]);
          acc[mf][nf] = mfma16(al[mf], bh2[nf], acc[mf][nf]);
          acc[mf][nf] = mfma16(ah[mf], bl2[nf], acc[mf][nf]);
        }
    }
    __syncthreads();
  }

  // fused prep epilogue: this wave's 64 columns are exactly one head
  const int hh = (n0 + nbase) >> 6;
  #pragma unroll
  for (int mf=0;mf<4;mf++){
    f32x4 v[4];
    #pragma unroll
    for (int nf=0;nf<4;nf++) v[nf] = acc_fence(acc[mf][nf]);
    #pragma unroll
    for (int r=0;r<4;r++){
      float ss = 0.f;
      #pragma unroll
      for (int nf=0;nf<4;nf++) ss += v[nf][r]*v[nf][r];
      ss += __shfl_xor(ss, 1); ss += __shfl_xor(ss, 2);
      ss += __shfl_xor(ss, 4); ss += __shfl_xor(ss, 8);
      // fold dim_head^-0.5 AND log2(e) into kn so attn uses raw v_exp (2^x)
      float scale = 0.18033688f / fmaxf(sqrtf(ss), 1e-6f);
      int m = m0 + mbase + mf*16 + lg*4 + r;
      int b = m >> 12, t = m & 4095;
      size_t rowb = ((((size_t)(b*8 + hh)) << 12) + t) * 64;
      #pragma unroll
      for (int nf=0;nf<4;nf++){
        float val = v[nf][r];
        u16 hbf = f2bf(val);
        size_t idx = rowb + nf*16 + lr;
        qb [idx] = hbf;
        qlo[idx] = f2bf(val - bf2f(hbf));
        kn [idx] = f2bf(val * scale);
      }
    }
  }
}

// ---------------- LSH hash: swapped-operand MFMA, lane-local argmax ----------------
__global__ __launch_bounds__(256) void k_hash2(
    const u16* __restrict__ qh, const u16* __restrict__ ql,
    const u16* __restrict__ rh, const u16* __restrict__ rl,
    int* __restrict__ bkt)
{
  const int tid = threadIdx.x;
  const int l = tid & 63, w = tid >> 6, lr = l & 15, lg = l >> 4;
  __shared__ __align__(16) u16 Rh[128*64];
  __shared__ __align__(16) u16 Rl[128*64];
  {
    const int row_s = tid >> 3, c8 = tid & 7;
    #pragma unroll
    for (int q = 0; q < 4; q++){
      int ra = q*32 + row_s;
      int cs = c8 ^ (ra & 7);
      gl_lds16(rh + ra*64 + cs*8, (char*)Rh + q*4096 + tid*16);
      gl_lds16(rl + ra*64 + cs*8, (char*)Rl + q*4096 + tid*16);
    }
  }
  const int blk = xcd_swz(blockIdx.x, gridDim.x);
  const int qrow = blk*64 + w*16 + lr;
  const size_t qoff = (size_t)qrow*64;
  i32x4 qhf[2], qlf[2];
  qhf[0] = *(const i32x4*)(qh + qoff + lg*8);
  qhf[1] = *(const i32x4*)(qh + qoff + 32 + lg*8);
  qlf[0] = *(const i32x4*)(ql + qoff + lg*8);
  qlf[1] = *(const i32x4*)(ql + qoff + 32 + lg*8);
  __syncthreads();

  f32x4 zero = {0.f,0.f,0.f,0.f};
  f32x4 acc[8];
  #pragma unroll
  for (int i=0;i<8;i++) acc[i] = zero;
  #pragma unroll
  for (int ks = 0; ks < 2; ks++){
    #pragma unroll
    for (int nf = 0; nf < 8; nf++){
      int row = nf*16 + lr;
      int off = (ks*64 + lg*16) ^ ((row & 7) << 4);
      i32x4 rhf = *(const i32x4*)((const char*)Rh + row*128 + off);
      i32x4 rlf = *(const i32x4*)((const char*)Rl + row*128 + off);
      acc[nf] = mfma16(rhf, qhf[ks], acc[nf]);
      acc[nf] = mfma16(rlf, qhf[ks], acc[nf]);
      acc[nf] = mfma16(rhf, qlf[ks], acc[nf]);
    }
  }

  const int bh = qrow >> 12, t = qrow & 4095;
  #pragma unroll
  for (int hh = 0; hh < 4; hh++){
    f32x4 v0 = acc_fence(acc[2*hh]);
    f32x4 v1 = acc_fence(acc[2*hh+1]);
    unsigned long long kmax = 0, kmin = 0;
    #pragma unroll
    for (int r = 0; r < 4; r++){
      int j0 = lg*4 + r, j1 = 16 + lg*4 + r;
      unsigned int mu0 = f2mono(v0[r]), mu1 = f2mono(v1[r]);
      unsigned long long a = ((unsigned long long)mu0 << 32) | (unsigned int)(31 - j0);
      unsigned long long b = ((unsigned long long)mu1 << 32) | (unsigned int)(31 - j1);
      if (a > kmax) kmax = a;
      if (b > kmax) kmax = b;
      unsigned long long c = ((unsigned long long)(~mu0) << 32) | (unsigned int)(31 - j0);
      unsigned long long d = ((unsigned long long)(~mu1) << 32) | (unsigned int)(31 - j1);
      if (c > kmin) kmin = c;
      if (d > kmin) kmin = d;
    }
    #pragma unroll
    for (int msk = 16; msk < 64; msk <<= 1){
      unsigned long long o1 = shfl_xor_u64(kmax, msk); if (o1 > kmax) kmax = o1;
      unsigned long long o2 = shfl_xor_u64(kmin, msk); if (o2 > kmin) kmin = o2;
    }
    if (lg == 0){
      float vmax = mono2f((unsigned int)(kmax >> 32));
      int jmax = 31 - (int)(kmax & 0xFFFFFFFFull);
      float vmin = mono2f(~(unsigned int)(kmin >> 32));
      int jmin = 31 - (int)(kmin & 0xFFFFFFFFull);
      int bucket = (vmax >= -vmin) ? jmax : 32 + jmin;
      bkt[((size_t)(bh*4 + hh) << 12) + t] = bucket;
    }
  }
}

// ---------------- stable counting sort per (bh, round) ----------------
__global__ __launch_bounds__(64) void k_sort(const int* __restrict__ buckets, int* __restrict__ st){
  const int grp = blockIdx.x;
  const int t = threadIdx.x;
  __shared__ int bkL[4096];
  __shared__ int hist[64][65];
  __shared__ int tot[64];
  const size_t gbase = ((size_t)grp) << 12;
  for (int i=0;i<64;i++)
    bkL[i*64 + t] = buckets[gbase + i*64 + t];   // coalesced
  #pragma unroll
  for (int b=0;b<64;b++) hist[t][b] = 0;
  __syncthreads();
  for (int i=0;i<64;i++){
    int b = bkL[t*64 + i];
    hist[t][b]++;
  }
  __syncthreads();
  { int run = 0;
    for (int tt=0; tt<64; tt++){ int v = hist[tt][t]; hist[tt][t] = run; run += v; }
    tot[t] = run; }
  __syncthreads();
  { int v = tot[t]; int incl = v;
    #pragma unroll
    for (int d=1; d<64; d<<=1){ int n = __shfl_up(incl, d, 64); if (t >= d) incl += n; }
    tot[t] = incl - v; }
  __syncthreads();
  const size_t obase = (((size_t)(grp>>2)) << 14) + ((size_t)(grp&3) << 12);
  for (int i=0;i<64;i++){
    int e = t*64 + i;
    int b = bkL[e];
    int dest = tot[b] + hist[t][b];
    hist[t][b]++;
    st[obase + dest] = e;
  }
}

// ---------------- chunked LSH attention: 32KB LDS (5 blocks/CU), no posk array ----------------
__global__ __launch_bounds__(256, 5) void k_attn(
    const u16* __restrict__ qb, const u16* __restrict__ kn, const u16* __restrict__ vB,
    const int* __restrict__ st, float* __restrict__ lgt_out, u16* __restrict__ bo)
{
  int flat = blockIdx.y * gridDim.x + blockIdx.x;
  flat = xcd_swz(flat, gridDim.x * gridDim.y);
  const int c = flat & 255, bh = flat >> 8;
  const int rnd = c >> 6;
  const int cprev = (c + 255) & 255;
  const int tid = threadIdx.x;
  const int l = tid & 63, w = tid >> 6, lr = l & 15, lg = l >> 4;

  __shared__ __align__(16) u16 Ks[128*64];   // 16KB
  __shared__ __align__(16) u16 Vt[64*128];   // 16KB, XOR-swizzled rows of 256B

  const size_t stbase = ((size_t)bh) << 14;
  const size_t kvbase = ((size_t)bh) << 12;

  // K staging: direct st reads, pre-swizzled global source, linear LDS dest
  {
    const int rsub = l >> 3, c8 = l & 7;
    #pragma unroll
    for (int q2 = 0; q2 < 4; q2++){
      int row = w*32 + q2*8 + rsub;
      int cc = (row < 64) ? c : cprev;
      int pos = st[stbase + (cc << 6) + (row & 63)];
      int cs = c8 ^ (row & 7);
      gl_lds16(kn + (kvbase + pos)*64 + cs*8,
               (char*)Ks + (w*4 + q2)*1024 + l*16);
    }
  }

  // Q fragments
  const int pos_q16 = st[stbase + (c << 6) + (w*16 + lr)];
  i32x4 qf[2];
  #pragma unroll
  for (int ks = 0; ks < 2; ks++)
    qf[ks] = *(const i32x4*)(qb + (kvbase + pos_q16)*64 + ks*32 + lg*8);

  // V gather + register transpose into XOR-swizzled Vt
  {
    const int pp = tid & 63, db = tid >> 6;
    const int q5 = pp & 15;
    const int K0 = (pp >> 4)*32 + 16*((q5 >> 1) & 1) + 4*(q5 >> 2) + 2*(q5 & 1);
    int cc0 = (K0 < 64) ? c : cprev;
    int p0 = st[stbase + (cc0 << 6) + (K0 & 63)];
    int p1 = st[stbase + (cc0 << 6) + ((K0 + 1) & 63)];
    const u16* r0 = vB + (kvbase + p0)*64 + db*16;
    const u16* r1 = vB + (kvbase + p1)*64 + db*16;
    uint4 a0 = *(const uint4*)r0, a1 = *(const uint4*)(r0 + 8);
    uint4 b0 = *(const uint4*)r1, b1 = *(const uint4*)(r1 + 8);
    uint av[8] = {a0.x,a0.y,a0.z,a0.w,a1.x,a1.y,a1.z,a1.w};
    uint bv[8] = {b0.x,b0.y,b0.z,b0.w,b1.x,b1.y,b1.z,b1.w};
    #pragma unroll
    for (int dd = 0; dd < 16; dd++){
      uint lo = (av[dd>>1] >> ((dd&1)*16)) & 0xFFFFu;
      uint hi = (bv[dd>>1] >> ((dd&1)*16)) & 0xFFFFu;
      int row = db*16 + dd;
      *(uint*)((char*)Vt + row*256 + ((pp*4) ^ ((row & 7) << 5))) = lo | (hi << 16);
    }
  }
  // boundary-chunk cross-round same-token mask data (rare: 1/64 blocks)
  const bool bdry = (c & 63) == 0;
  int pkprev[4][4];
  if (bdry){
    #pragma unroll
    for (int nf2=0; nf2<4; nf2++)
      #pragma unroll
      for (int r=0;r<4;r++)
        pkprev[nf2][r] = st[stbase + (cprev << 6) + nf2*16 + lg*4 + r];
  }
  __syncthreads();

  f32x4 zero = {0.f,0.f,0.f,0.f};
  f32x4 s[8];
  #pragma unroll
  for (int i=0;i<8;i++) s[i] = zero;
  __builtin_amdgcn_s_setprio(1);
  #pragma unroll
  for (int ks = 0; ks < 2; ks++){
    #pragma unroll
    for (int nf = 0; nf < 8; nf++){
      int row = nf*16 + lr;
      i32x4 kf = *(const i32x4*)((const char*)Ks + row*128 + ((ks*64 + lg*16) ^ ((row&7)<<4)));
      s[nf] = mfma16(kf, qf[ks], s[nf]);
    }
  }
  __builtin_amdgcn_s_setprio(0);

  // max-free softmax: S pre-scaled by 0.125*log2e -> p = 2^S, cannot overflow
  float p[8][4];
  float sum = 0.f;
  #pragma unroll
  for (int nf=0;nf<8;nf++){
    f32x4 t = acc_fence(s[nf]);
    #pragma unroll
    for (int r=0;r<4;r++){
      float e = __builtin_amdgcn_exp2f(t[r]);
      if (nf == w && (lg*4 + r) == lr) e = 0.f;                          // self (same slot)
      if (nf >= 4 && bdry && pkprev[nf-4][r] == pos_q16) e = 0.f;        // cross-round same token
      p[nf][r] = e;
      sum += e;
    }
  }
  sum += __shfl_xor(sum, 16);
  sum += __shfl_xor(sum, 32);
  float lv = logf(sum);
  float inv = 1.f / sum;
  if (l < 16)
    lgt_out[((((size_t)bh) << 12) + pos_q16)*4 + rnd] = lv;

  i32x4 pa[4];
  #pragma unroll
  for (int ks=0;ks<4;ks++){
    uint w0 = cvtpk_bf16(p[2*ks][0],   p[2*ks][1]);
    uint w1 = cvtpk_bf16(p[2*ks][2],   p[2*ks][3]);
    uint w2 = cvtpk_bf16(p[2*ks+1][0], p[2*ks+1][1]);
    uint w3 = cvtpk_bf16(p[2*ks+1][2], p[2*ks+1][3]);
    i32x4 t = {(int)w0,(int)w1,(int)w2,(int)w3};
    pa[ks] = t;
  }

  f32x4 o[4];
  #pragma unroll
  for (int i=0;i<4;i++) o[i] = zero;
  __builtin_amdgcn_s_setprio(1);
  #pragma unroll
  for (int ks=0;ks<4;ks++){
    #pragma unroll
    for (int nf=0;nf<4;nf++){
      int row = nf*16 + lr;
      i32x4 vf = *(const i32x4*)((const char*)Vt + row*256 + ((ks*64 + lg*16) ^ ((row & 7) << 5)));
      o[nf] = mfma16(pa[ks], vf, o[nf]);
    }
  }
  __builtin_amdgcn_s_setprio(0);
  float invq[4]; int posq[4];
  #pragma unroll
  for (int r=0;r<4;r++){
    invq[r] = __shfl(inv, lg*4 + r, 64);
    posq[r] = __shfl(pos_q16, lg*4 + r, 64);
  }
  #pragma unroll
  for (int nf=0;nf<4;nf++){
    f32x4 ov = acc_fence(o[nf]);
    #pragma unroll
    for (int r=0;r<4;r++){
      bo[((((size_t)bh << 12) + posq[r]))*256 + rnd*64 + nf*16 + lr] = f2bf(ov[r] * invq[r]);
    }
  }
}

// ---------------- combine hash rounds (token-major bo/lgt) ----------------
__global__ __launch_bounds__(256) void k_combine(const u16* __restrict__ bo, const float* __restrict__ lgt,
                                                 u16* __restrict__ attn){
  const int wid = blockIdx.x * 4 + (threadIdx.x >> 6);
  const int l = threadIdx.x & 63;
  const int bh = wid >> 12, t = wid & 4095;
  const size_t tb = (((size_t)bh) << 12) + t;
  float4 lg4 = *(const float4*)(lgt + tb*4);
  float m = fmaxf(fmaxf(lg4.x,lg4.y), fmaxf(lg4.z,lg4.w));
  float w0 = __expf(lg4.x-m), w1 = __expf(lg4.y-m), w2 = __expf(lg4.z-m), w3 = __expf(lg4.w-m);
  float inv = 1.f / (w0+w1+w2+w3);
  const u16* bp = bo + tb*256;
  float o = w0 * bf2f(bp[l]) + w1 * bf2f(bp[64+l]) + w2 * bf2f(bp[128+l]) + w3 * bf2f(bp[192+l]);
  o *= inv;
  int b = bh >> 3, h = bh & 7;
  attn[((((size_t)b) << 12) + t) * 512 + h*64 + l] = f2bf(o);
}

// ---------------- residual + LayerNorm: a always bf16 ----------------
// RESF=1: res fp32 (x), write bf16 ob. RESF=0: res bf16 (hb), write fp32 of.
template<int RESF>
__global__ __launch_bounds__(256) void k_ln(const u16* __restrict__ a,
                                            const float* __restrict__ resf, const u16* __restrict__ resb,
                                            const float* __restrict__ g, const float* __restrict__ bb,
                                            float* __restrict__ of, u16* __restrict__ ob){
  const int row = blockIdx.x*4 + (threadIdx.x >> 6);
  const int l = threadIdx.x & 63;
  const size_t base = (size_t)row*512 + l*8;
  uint4 aa = *(const uint4*)(a + base);
  uint aw[4] = {aa.x, aa.y, aa.z, aa.w};
  float av[8];
  #pragma unroll
  for (int j=0;j<4;j++){
    av[2*j]   = bf2f((u16)(aw[j] & 0xFFFF));
    av[2*j+1] = bf2f((u16)(aw[j] >> 16));
  }
  float rv[8];
  if (RESF){
    float4 r0 = *(const float4*)(resf + base);
    float4 r1 = *(const float4*)(resf + base + 4);
    rv[0]=r0.x; rv[1]=r0.y; rv[2]=r0.z; rv[3]=r0.w;
    rv[4]=r1.x; rv[5]=r1.y; rv[6]=r1.z; rv[7]=r1.w;
  } else {
    uint4 rr = *(const uint4*)(resb + base);
    uint rw[4] = {rr.x, rr.y, rr.z, rr.w};
    #pragma unroll
    for (int j=0;j<4;j++){
      rv[2*j]   = bf2f((u16)(rw[j] & 0xFFFF));
      rv[2*j+1] = bf2f((u16)(rw[j] >> 16));
    }
  }
  float v[8];
  #pragma unroll
  for (int j=0;j<8;j++) v[j] = av[j] + rv[j];
  float sum = 0.f;
  #pragma unroll
  for (int j=0;j<8;j++) sum += v[j];
  #pragma unroll
  for (int msk=1; msk<64; msk<<=1) sum += __shfl_xor(sum, msk);
  float mean = sum * (1.f/512.f);
  float ss = 0.f;
  #pragma unroll
  for (int j=0;j<8;j++){ float d = v[j]-mean; ss += d*d; }
  #pragma unroll
  for (int msk=1; msk<64; msk<<=1) ss += __shfl_xor(ss, msk);
  float rstd = rsqrtf(ss * (1.f/512.f) + 1e-6f);
  float4 g0 = *(const float4*)(g + l*8),  g1 = *(const float4*)(g + l*8 + 4);
  float4 b0 = *(const float4*)(bb + l*8), b1 = *(const float4*)(bb + l*8 + 4);
  float gv[8] = {g0.x,g0.y,g0.z,g0.w,g1.x,g1.y,g1.z,g1.w};
  float bv[8] = {b0.x,b0.y,b0.z,b0.w,b1.x,b1.y,b1.z,b1.w};
  float y[8];
  #pragma unroll
  for (int j=0;j<8;j++) y[j] = (v[j]-mean)*rstd*gv[j] + bv[j];
  if (RESF){
    #pragma unroll
    for (int j=0;j<8;j++) ob[base+j] = f2bf(y[j]);
  } else {
    #pragma unroll
    for (int j=0;j<8;j++) of[base+j] = y[j];
  }
}

extern "C" void kernel_launch(void* const* d_in, const int* in_sizes, int n_in,
                              void* d_out, int out_size, void* d_ws, size_t ws_size,
                              hipStream_t stream) {
  const float* x     = (const float*)d_in[0];
  const float* rot   = (const float*)d_in[1];
  const float* w_qk  = (const float*)d_in[2];
  const float* w_v   = (const float*)d_in[3];
  const float* w_out = (const float*)d_in[4];
  const float* b_out = (const float*)d_in[5];
  const float* ln1_g = (const float*)d_in[6];
  const float* ln1_b = (const float*)d_in[7];
  const float* w1    = (const float*)d_in[8];
  const float* b1    = (const float*)d_in[9];
  const float* w2    = (const float*)d_in[10];
  const float* b2    = (const float*)d_in[11];
  const float* ln2_g = (const float*)d_in[12];
  const float* ln2_b = (const float*)d_in[13];
  float* out = (float*)d_out;

  char* p = (char*)d_ws;
  u16*   xh   = (u16*)(p);                    // x-hi   | later: hb (bf16 h)
  u16*   xl   = (u16*)(p + 16777216);         // x-lo   | later: attnc, then f bf16
  u16*   wqkh = (u16*)(p + 33554432);
  u16*   wqkl = (u16*)(p + 34078720);
  u16*   wvb  = (u16*)(p + 34603008);
  u16*   wob  = (u16*)(p + 35127296);
  u16*   w1b  = (u16*)(p + 35651584);
  u16*   w2b  = (u16*)(p + 37748736);
  u16*   qbuf = (u16*)(p + 39845888);         // qk bf16 hi (head layout) | later: proj bf16
  u16*   knb  = (u16*)(p + 56623104);         // kn bf16 (head layout, pre-scaled 0.125*log2e)
  u16*   vb   = (u16*)(p + 73400320);
  int*   bkt  = (int*)(p + 90177536);
  int*   stb  = (int*)(p + 92274688);
  float* lgt  = (float*)(p + 94371840);
  u16*   bo   = (u16*)(p + 96468992);         // 67 MB | early: qlo + rot buffers, later: ffn hidden
  // aliases (non-overlapping lifetimes)
  u16*   qlo   = bo;                          // bo[0..16MB): dead before k_attn writes bo
  u16*   rothi = (u16*)(p + 96468992 + 16777216);          // bo+16MB, 16KB
  u16*   rotlo = (u16*)(p + 96468992 + 16777216 + 16384);  // consumed by hash before attn
  u16*   attnc = xl;
  u16*   projb = qbuf;                        // out-proj bf16 (qbuf dead after attn)
  u16*   fb    = xl;                          // FFN2 bf16 (xl dead after out-proj)
  u16*   hb    = xh;
  u16*   hid   = bo;

  // 1) x split (hi/lo bf16)
  k_split<<<8192, 256, 0, stream>>>(x, xh, xl, 16384*512/4);
  // 2) all weight converts + rot transpose/split in one dispatch
  k_wprep<<<2848, 256, 0, stream>>>(w_qk, w_v, w_out, w1, w2, rot,
                                    wqkh, wqkl, wvb, wob, w1b, w2b, rothi, rotlo);
  // 3) qk GEMM (BK=64, 3-term split) + fused prep epilogue
  k_gemmqk<<<dim3(4,128), 256, 0, stream>>>(xh, xl, wqkh, wqkl, qbuf, qlo, knb);
  // 4) v = x @ w_v^T, head layout bf16
  k_gemm<3><<<dim3(4,128), 256, 0, stream>>>(xh, wvb, nullptr, nullptr, vb, 16384, 512, 512);
  // 5) LSH hash: S^T = rot x qk (3-term split), lane-local argmax -> buckets
  k_hash2<<<2048, 256, 0, stream>>>(qbuf, qlo, rothi, rotlo, bkt);
  // 6) stable counting sort per (bh, round)
  k_sort<<<128, 64, 0, stream>>>(bkt, stb);
  // 7) chunked attention (5 blocks/CU)
  k_attn<<<dim3(256,32), 256, 0, stream>>>(qbuf, knb, vb, stb, lgt, bo);
  // 8) combine rounds -> (b,t,512) bf16
  k_combine<<<32768, 256, 0, stream>>>(bo, lgt, attnc);
  // 9) out projection (+bias) -> bf16 projb
  k_gemm<4><<<dim3(4,128), 256, 0, stream>>>(attnc, wob, b_out, nullptr, projb, 16384, 512, 512);
  // 10) h = LN(proj + x) -> bf16 hb
  k_ln<1><<<4096, 256, 0, stream>>>(projb, x, nullptr, ln1_g, ln1_b, nullptr, hb);
  // 11) hidden = relu(h @ w1^T + b1) bf16
  k_gemm<1><<<dim3(16,128), 256, 0, stream>>>(hb, w1b, b1, nullptr, hid, 16384, 2048, 512);
  // 12) f = hidden @ w2^T + b2 -> bf16 fb
  k_gemm<4><<<dim3(4,128), 256, 0, stream>>>(hid, w2b, b2, nullptr, fb, 16384, 512, 2048);
  // 13) out = LN(f + h) -> fp32 d_out
  k_ln<0><<<4096, 256, 0, stream>>>(fb, nullptr, hb, ln2_g, ln2_b, out, nullptr);
}